// Round 11
// baseline (643.182 us; speedup 1.0000x reference)
//
#include <hip/hip_runtime.h>
#include <hip/hip_bf16.h>
#include <math.h>

// Problem constants (fixed by the reference)
#define N_NODES 50000
#define N_EDGES 800000
#define NODE_DIM 3
#define EDGE_DIM 32
#define HIDDEN 128
#define NUM_GRAPHS 256
#define ZIN (2*HIDDEN + EDGE_DIM)   // 288
#define NPAD 50176                  // 196 * 256 (padded node count for scan)

#define LOG2E 1.44269504088896f
#define LN2   0.69314718055995f

typedef __attribute__((ext_vector_type(8))) short short8;
typedef __attribute__((ext_vector_type(4))) float f32x4;

// fp32 -> bf16 (RNE), finite inputs
__device__ __forceinline__ unsigned short f2bf(float x) {
    unsigned u = __float_as_uint(x);
    u += 0x7FFFu + ((u >> 16) & 1u);
    return (unsigned short)(u >> 16);
}
// low/high bf16 of a packed uint -> fp32
__device__ __forceinline__ float bf_lo(unsigned u) { return __uint_as_float(u << 16); }
__device__ __forceinline__ float bf_hi(unsigned u) { return __uint_as_float(u & 0xFFFF0000u); }

// ---------------------------------------------------------------------------
// conv1 (dst-sorted + log2-domain). Also emits EAb: bf16 edge attrs in
// SORTED order (64 B/edge) so the edge kernels read them coalesced with no
// eid indirection. Numerically identical (same f2bf of same fp32 values).
// ---------------------------------------------------------------------------
__global__ __launch_bounds__(256) void conv1_sorted_kernel(
    const float* __restrict__ x, const float* __restrict__ EA,
    const int4* __restrict__ epack,
    const float* __restrict__ Wf1, const float* __restrict__ bf1,
    const float* __restrict__ Ws1, const float* __restrict__ bs1,
    float* __restrict__ agg0, unsigned short* __restrict__ EAb)
{
    __shared__ float WfL[38*3], WsL[38*3], bfL[3], bsL[3];
    __shared__ float msgL[256*5];   // [edge][ch], stride 5 (conflict-free)
    __shared__ int   pdL[256];

    if (threadIdx.x < 114) {
        WfL[threadIdx.x] = Wf1[threadIdx.x] * LOG2E;
        WsL[threadIdx.x] = Ws1[threadIdx.x] * LOG2E;
    }
    if (threadIdx.x < 3) {
        bfL[threadIdx.x] = bf1[threadIdx.x] * LOG2E;
        bsL[threadIdx.x] = bs1[threadIdx.x] * LOG2E;
    }
    __syncthreads();

    const int p = blockIdx.x * 256 + threadIdx.x;   // 800000 % 256 == 0
    int4 e = epack[p];
    const int eid = e.x, s = e.y, d = e.z;
    pdL[threadIdx.x] = d;

    float z[38];
    z[0] = x[d*3+0]; z[1] = x[d*3+1]; z[2] = x[d*3+2];
    z[3] = x[s*3+0]; z[4] = x[s*3+1]; z[5] = x[s*3+2];
    const float4* ep = (const float4*)(EA + (size_t)eid * EDGE_DIM);
    #pragma unroll
    for (int q = 0; q < 8; ++q) {
        float4 v = ep[q];
        z[6+4*q+0] = v.x; z[6+4*q+1] = v.y; z[6+4*q+2] = v.z; z[6+4*q+3] = v.w;
    }

    if (EAb) {   // uniform branch: emit sorted bf16 edge attrs
        unsigned short vals[32];
        #pragma unroll
        for (int j = 0; j < 32; ++j) vals[j] = f2bf(z[6+j]);
        unsigned short* dst = EAb + (size_t)p * 32;
        *(short8*)(dst + 0)  = *(short8*)(vals + 0);
        *(short8*)(dst + 8)  = *(short8*)(vals + 8);
        *(short8*)(dst + 16) = *(short8*)(vals + 16);
        *(short8*)(dst + 24) = *(short8*)(vals + 24);
    }

    float f[3], g[3];
    #pragma unroll
    for (int c = 0; c < 3; ++c) { f[c] = bfL[c]; g[c] = bsL[c]; }
    #pragma unroll
    for (int j = 0; j < 38; ++j) {
        #pragma unroll
        for (int c = 0; c < 3; ++c) {
            f[c] += z[j] * WfL[j*3+c];
            g[c] += z[j] * WsL[j*3+c];
        }
    }
    #pragma unroll
    for (int c = 0; c < 3; ++c) {
        float sig = __builtin_amdgcn_rcpf(1.0f + __builtin_amdgcn_exp2f(-f[c]));
        float sp  = __builtin_amdgcn_logf(1.0f + __builtin_amdgcn_exp2f(g[c]));
        msgL[threadIdx.x*5 + c] = sig * sp;
    }
    __syncthreads();

    // Segmented reduction: 48 threads = 3 channels x 16 segments of 16 edges.
    if (threadIdx.x < 48) {
        const int c   = threadIdx.x % 3;
        const int seg = threadIdx.x / 3;
        const int base = seg * 16;
        float acc = 0.0f;
        int cur = pdL[base];
        #pragma unroll 4
        for (int i = 0; i < 16; ++i) {
            int dd = pdL[base + i];
            float v = msgL[(base + i)*5 + c];
            if (dd != cur) {
                atomicAdd(agg0 + (size_t)cur*3 + c, acc);
                acc = 0.0f; cur = dd;
            }
            acc += v;
        }
        atomicAdd(agg0 + (size_t)cur*3 + c, acc);
    }
}

// ---------------------------------------------------------------------------
// hist + weight repack fused. NEW: stores rank[e] (the atomicAdd return) so
// scatter needs no atomics; rank parks in the Pb region (overwritten later).
// ---------------------------------------------------------------------------
__global__ __launch_bounds__(256) void hist_repack_kernel(
    const int* __restrict__ ei, int* __restrict__ hist, int* __restrict__ rank,
    const float* __restrict__ Wf, const float* __restrict__ Ws,
    unsigned short* __restrict__ Bfrag, unsigned short* __restrict__ BE)
{
    int e = blockIdx.x * 256 + threadIdx.x;
    if (e < N_EDGES) rank[e] = atomicAdd(&hist[ei[N_EDGES + e]], 1);

    int idx = e;
    if (idx < 2*32*4*64) {          // node-path: 16384 frags
        int lane = idx & 63;
        int kc   = (idx >> 6) & 3;
        int nt   = (idx >> 8) & 31;
        int l    = idx >> 13;
        const float* wf  = Wf + (size_t)l * ZIN * HIDDEN;
        const float* wsp = Ws + (size_t)l * ZIN * HIDDEN;
        int n = nt*16 + (lane & 15);
        int half = n >> 8;
        int within = n & 255;
        int cc = within >> 1;
        int t = within & 1;
        const float* W = t ? wsp : wf;
        unsigned short vals[8];
        #pragma unroll
        for (int j = 0; j < 8; ++j) {
            int k = kc*32 + (lane >> 4)*8 + j;
            vals[j] = f2bf(W[(size_t)(half*128 + k)*128 + cc] * LOG2E);
        }
        *(short8*)(Bfrag + (size_t)idx * 8) = *(short8*)vals;
    } else if (idx < 2*32*4*64 + 2*16*64) {   // edge-path: 2048 frags
        int i2 = idx - 2*32*4*64;
        int lane = i2 & 63;
        int nt   = (i2 >> 6) & 15;
        int l    = i2 >> 10;
        const float* W = ((nt & 8) ? Ws : Wf) + (size_t)l * ZIN * HIDDEN + 256*128;
        int c = (nt & 7)*16 + (lane & 15);
        unsigned short vals[8];
        #pragma unroll
        for (int j = 0; j < 8; ++j) {
            int k = (lane >> 4)*8 + j;
            vals[j] = f2bf(W[(size_t)k*128 + c] * LOG2E);
        }
        *(short8*)(BE + (size_t)i2 * 8) = *(short8*)vals;
    }
}

__global__ __launch_bounds__(256) void scanA_kernel(
    const int* __restrict__ hist, int* __restrict__ cursor, int* __restrict__ btot)
{
    __shared__ int tmp[256];
    int t = threadIdx.x;
    int i = blockIdx.x * 256 + t;
    int v = hist[i];
    tmp[t] = v;
    __syncthreads();
    #pragma unroll
    for (int off = 1; off < 256; off <<= 1) {
        int y = (t >= off) ? tmp[t - off] : 0;
        __syncthreads();
        if (t >= off) tmp[t] += y;
        __syncthreads();
    }
    cursor[i] = tmp[t] - v;
    if (t == 255) btot[blockIdx.x] = tmp[t];
}

__global__ __launch_bounds__(256) void scanB_kernel(int* __restrict__ btot)
{
    __shared__ int tmp[256];
    int t = threadIdx.x;
    int v = btot[t];
    tmp[t] = v;
    __syncthreads();
    #pragma unroll
    for (int off = 1; off < 256; off <<= 1) {
        int y = (t >= off) ? tmp[t - off] : 0;
        __syncthreads();
        if (t >= off) tmp[t] += y;
        __syncthreads();
    }
    btot[t] = tmp[t] - v;
}

// Scatter: one int4 store per edge (eid, src, dst, 0) at its sorted slot.
// NEW: slot = cursor[d] + rank[e] + btot[d>>8] -- no atomics, deterministic.
__global__ __launch_bounds__(256) void scatter_kernel(
    const int* __restrict__ ei, const int* __restrict__ cursor,
    const int* __restrict__ btot, const int* __restrict__ rank,
    int4* __restrict__ epack)
{
    int e = blockIdx.x * 256 + threadIdx.x;
    if (e >= N_EDGES) return;
    int s = ei[e];
    int d = ei[N_EDGES + e];
    int p = cursor[d] + rank[e] + btot[d >> 8];
    epack[p] = make_int4(e, s, d, 0);
}

// ---------------------------------------------------------------------------
// gemm0 with proj fused: A-row = relu(bp + (x+ln2*agg0)@Wp), computed
// in-block from the 3-dim inputs (Wp/bp in LDS); H stored once (colBase==0).
// Then Pb = bf16(A @ (log2e*Wcat) + log2e*bias) as before.
// ---------------------------------------------------------------------------
__global__ __launch_bounds__(256) void gemm0_fused_kernel(
    const float* __restrict__ x, const float* __restrict__ agg0,
    const float* __restrict__ Wp, const float* __restrict__ bp,
    const unsigned short* __restrict__ Bfrag,
    const float* __restrict__ bf, const float* __restrict__ bs,
    unsigned short* __restrict__ Pb, float* __restrict__ H)
{
    __shared__ float WpL[384], bpL[128];
    WpL[threadIdx.x] = Wp[threadIdx.x];
    if (threadIdx.x < 128) {
        WpL[256 + threadIdx.x] = Wp[256 + threadIdx.x];
        bpL[threadIdx.x] = bp[threadIdx.x];
    }
    __syncthreads();

    const int lane = threadIdx.x & 63;
    const int wave = threadIdx.x >> 6;
    const int m    = lane & 15;
    const int quad = lane >> 4;
    const int rowA = blockIdx.y * 64 + wave * 16 + m;
    const int rowX = rowA < N_NODES ? rowA : N_NODES - 1;   // clamp input reads
    const int colBase = blockIdx.x * 256;

    float h0 = fmaf(agg0[rowX*3+0], LN2, x[rowX*3+0]);
    float h1 = fmaf(agg0[rowX*3+1], LN2, x[rowX*3+1]);
    float h2 = fmaf(agg0[rowX*3+2], LN2, x[rowX*3+2]);

    short8 a[4];
    #pragma unroll
    for (int kc = 0; kc < 4; ++kc) {
        float vv[8];
        unsigned short t[8];
        #pragma unroll
        for (int i = 0; i < 8; ++i) {
            int col = kc*32 + quad*8 + i;
            float v = bpL[col] + h0*WpL[col] + h1*WpL[128+col] + h2*WpL[256+col];
            v = fmaxf(v, 0.0f);
            vv[i] = v;
            t[i] = f2bf(v);
        }
        a[kc] = *(short8*)t;
        if (colBase == 0 && rowA < N_NODES) {
            float* hp = H + (size_t)rowA * 128 + kc*32 + quad*8;
            *(float4*)hp       = make_float4(vv[0], vv[1], vv[2], vv[3]);
            *(float4*)(hp + 4) = make_float4(vv[4], vv[5], vv[6], vv[7]);
        }
    }

    f32x4 acc[16];
    #pragma unroll
    for (int nt = 0; nt < 16; ++nt) {
        float bias = 0.0f;
        if (colBase == 0) {
            int col = nt*16 + m;
            bias = ((col & 1) ? bs[col >> 1] : bf[col >> 1]) * LOG2E;
        }
        acc[nt] = (f32x4){bias, bias, bias, bias};
    }

    #pragma unroll
    for (int nt = 0; nt < 16; ++nt) {
        int ntg = (colBase >> 4) + nt;
        const unsigned short* bpf = Bfrag + ((size_t)(ntg*4) * 64 + lane) * 8;
        #pragma unroll
        for (int kc = 0; kc < 4; ++kc) {
            short8 b = *(const short8*)(bpf + (size_t)kc * 64 * 8);
            acc[nt] = __builtin_amdgcn_mfma_f32_16x16x32_bf16(a[kc], b, acc[nt], 0, 0, 0);
        }
    }

    const int rowC = blockIdx.y * 64 + wave * 16 + quad * 4;
    #pragma unroll
    for (int nt = 0; nt < 16; ++nt) {
        int col = colBase + nt*16 + m;
        #pragma unroll
        for (int r = 0; r < 4; ++r) {
            int row = rowC + r;
            if (row < N_NODES) Pb[(size_t)row * 512 + col] = f2bf(acc[nt][r]);
        }
    }
}

// ---------------------------------------------------------------------------
// Node MFMA GEMM (layer 1): A = relu(H + ln2*aggIn), fused into the A-load.
// ---------------------------------------------------------------------------
__global__ __launch_bounds__(256) void gemm_mfma(
    const float* __restrict__ H, const float* __restrict__ aggIn,
    const unsigned short* __restrict__ Bfrag,
    const float* __restrict__ bf, const float* __restrict__ bs,
    unsigned short* __restrict__ Pb)
{
    const int lane = threadIdx.x & 63;
    const int wave = threadIdx.x >> 6;
    const int m    = lane & 15;
    const int quad = lane >> 4;
    const int rowA = blockIdx.y * 64 + wave * 16 + m;   // OOB rows read ws (safe); stores masked
    const int colBase = blockIdx.x * 256;

    const float* hrow = H + (size_t)rowA * 128;
    const float* arow = aggIn + (size_t)rowA * 128;
    short8 a[4];
    #pragma unroll
    for (int kc = 0; kc < 4; ++kc) {
        float4 v0 = *(const float4*)(hrow + kc*32 + quad*8);
        float4 v1 = *(const float4*)(hrow + kc*32 + quad*8 + 4);
        float4 a0 = *(const float4*)(arow + kc*32 + quad*8);
        float4 a1 = *(const float4*)(arow + kc*32 + quad*8 + 4);
        v0.x = fmaxf(fmaf(a0.x, LN2, v0.x), 0.f); v0.y = fmaxf(fmaf(a0.y, LN2, v0.y), 0.f);
        v0.z = fmaxf(fmaf(a0.z, LN2, v0.z), 0.f); v0.w = fmaxf(fmaf(a0.w, LN2, v0.w), 0.f);
        v1.x = fmaxf(fmaf(a1.x, LN2, v1.x), 0.f); v1.y = fmaxf(fmaf(a1.y, LN2, v1.y), 0.f);
        v1.z = fmaxf(fmaf(a1.z, LN2, v1.z), 0.f); v1.w = fmaxf(fmaf(a1.w, LN2, v1.w), 0.f);
        unsigned short t[8];
        t[0]=f2bf(v0.x); t[1]=f2bf(v0.y); t[2]=f2bf(v0.z); t[3]=f2bf(v0.w);
        t[4]=f2bf(v1.x); t[5]=f2bf(v1.y); t[6]=f2bf(v1.z); t[7]=f2bf(v1.w);
        a[kc] = *(short8*)t;
    }

    f32x4 acc[16];
    #pragma unroll
    for (int nt = 0; nt < 16; ++nt) {
        float bias = 0.0f;
        if (colBase == 0) {
            int col = nt*16 + m;
            bias = ((col & 1) ? bs[col >> 1] : bf[col >> 1]) * LOG2E;
        }
        acc[nt] = (f32x4){bias, bias, bias, bias};
    }

    #pragma unroll
    for (int nt = 0; nt < 16; ++nt) {
        int ntg = (colBase >> 4) + nt;
        const unsigned short* bp = Bfrag + ((size_t)(ntg*4) * 64 + lane) * 8;
        #pragma unroll
        for (int kc = 0; kc < 4; ++kc) {
            short8 b = *(const short8*)(bp + (size_t)kc * 64 * 8);
            acc[nt] = __builtin_amdgcn_mfma_f32_16x16x32_bf16(a[kc], b, acc[nt], 0, 0, 0);
        }
    }

    const int rowC = blockIdx.y * 64 + wave * 16 + quad * 4;
    #pragma unroll
    for (int nt = 0; nt < 16; ++nt) {
        int col = colBase + nt*16 + m;
        #pragma unroll
        for (int r = 0; r < 4; ++r) {
            int row = rowC + r;
            if (row < N_NODES) Pb[(size_t)row * 512 + col] = f2bf(acc[nt][r]);
        }
    }
}

// ---------------------------------------------------------------------------
// Fused edge kernel, v17: v16's depth-2 named-scalar gather batching, PINNED
// with sched_barrier(0) so the scheduler cannot re-sink the loads to their
// uses (R9 showed it did: VGPR stayed 32). Loads stay clustered above the
// fence; combines/MFMA below. Reduce unchanged (4x16 segments, interior-run
// plain stores).
// ---------------------------------------------------------------------------
__global__ __launch_bounds__(256, 8) void edge_kernel(
    const unsigned short* __restrict__ Pb, const float* __restrict__ EA,
    const unsigned short* __restrict__ EAb,
    const int4* __restrict__ epack,
    const unsigned short* __restrict__ BE,
    float* __restrict__ agg)
{
    __shared__ float msgL[64*68];           // 17.4 KB, [c-row][swizzled 4-edge chunks]
    __shared__ int pdL[64];
    __shared__ unsigned bmaskL[2];

    if (threadIdx.x < 64) {
        const int t = threadIdx.x;
        int d = epack[blockIdx.x*64 + t].z;
        pdL[t] = d;
        bool b = (t & 15) ? (d != pdL[t-1]) : false;   // zero bits 0,16,32,48 (seg starts)
        unsigned long long bal = __ballot(b);
        if (t == 0) { bmaskL[0] = (unsigned)bal; bmaskL[1] = (unsigned)(bal >> 32); }
    }

    const int lane = threadIdx.x & 63;
    const int wave = threadIdx.x >> 6;
    const int m    = lane & 15;
    const int quad = lane >> 4;
    const int p0   = blockIdx.x * 64 + wave * 16;   // 800000 % 64 == 0

    // A-frag: this lane's edge attrs (bf16)
    short8 a;
    if (EAb) {   // direct coalesced load, address known at entry
        a = *(const short8*)(EAb + (size_t)(p0 + m) * 32 + quad*8);
    } else {
        int eid = epack[p0 + m].x;
        const float* ea = EA + (size_t)eid * EDGE_DIM + quad*8;
        float4 v0 = *(const float4*)ea;
        float4 v1 = *(const float4*)(ea + 4);
        unsigned short t[8];
        t[0]=f2bf(v0.x); t[1]=f2bf(v0.y); t[2]=f2bf(v0.z); t[3]=f2bf(v0.w);
        t[4]=f2bf(v1.x); t[5]=f2bf(v1.y); t[6]=f2bf(v1.z); t[7]=f2bf(v1.w);
        a = *(short8*)t;
    }

    // Per-r base pointers: nt offsets become compile-time immediates.
    const unsigned short* pdp[4];
    const unsigned short* psp[4];
    #pragma unroll
    for (int r = 0; r < 4; ++r) {
        int4 e = epack[p0 + quad*4 + r];
        pdp[r] = Pb + (size_t)e.z * 512 + 2*m;
        psp[r] = Pb + (size_t)e.y * 512 + 256 + 2*m;
    }

    const short8* BEv = (const short8*)BE;   // 16 KB, L1-resident
    const int chunk  = wave*4 + quad;        // this thread's 4-edge chunk (0..15)
    const int c2  = threadIdx.x & 63;        // reduce: channel row
    const int seg = threadIdx.x >> 6;        // reduce: 16-edge segment (== wave)
    const int chunkp = (chunk + 2*m) & 15;   // rotate-swizzle

    #pragma unroll
    for (int half = 0; half < 2; ++half) {
        #pragma unroll
        for (int pair = 0; pair < 2; ++pair) {
            const int ntA = half*4 + pair*2;
            const int ntB = ntA + 1;
            // ---- batch-issue 16 gather loads (named scalars) ----
            unsigned pdA0 = *(const unsigned*)(pdp[0] + ntA*32);
            unsigned psA0 = *(const unsigned*)(psp[0] + ntA*32);
            unsigned pdA1 = *(const unsigned*)(pdp[1] + ntA*32);
            unsigned psA1 = *(const unsigned*)(psp[1] + ntA*32);
            unsigned pdA2 = *(const unsigned*)(pdp[2] + ntA*32);
            unsigned psA2 = *(const unsigned*)(psp[2] + ntA*32);
            unsigned pdA3 = *(const unsigned*)(pdp[3] + ntA*32);
            unsigned psA3 = *(const unsigned*)(psp[3] + ntA*32);
            unsigned pdB0 = *(const unsigned*)(pdp[0] + ntB*32);
            unsigned psB0 = *(const unsigned*)(psp[0] + ntB*32);
            unsigned pdB1 = *(const unsigned*)(pdp[1] + ntB*32);
            unsigned psB1 = *(const unsigned*)(psp[1] + ntB*32);
            unsigned pdB2 = *(const unsigned*)(pdp[2] + ntB*32);
            unsigned psB2 = *(const unsigned*)(psp[2] + ntB*32);
            unsigned pdB3 = *(const unsigned*)(pdp[3] + ntB*32);
            unsigned psB3 = *(const unsigned*)(psp[3] + ntB*32);
            // Fence: loads above may NOT sink below; compute below may not hoist.
            __builtin_amdgcn_sched_barrier(0);

            f32x4 accFA, accSA, accFB, accSB;
            accFA[0] = bf_lo(pdA0) + bf_lo(psA0); accSA[0] = bf_hi(pdA0) + bf_hi(psA0);
            accFA[1] = bf_lo(pdA1) + bf_lo(psA1); accSA[1] = bf_hi(pdA1) + bf_hi(psA1);
            accFA[2] = bf_lo(pdA2) + bf_lo(psA2); accSA[2] = bf_hi(pdA2) + bf_hi(psA2);
            accFA[3] = bf_lo(pdA3) + bf_lo(psA3); accSA[3] = bf_hi(pdA3) + bf_hi(psA3);
            accFB[0] = bf_lo(pdB0) + bf_lo(psB0); accSB[0] = bf_hi(pdB0) + bf_hi(psB0);
            accFB[1] = bf_lo(pdB1) + bf_lo(psB1); accSB[1] = bf_hi(pdB1) + bf_hi(psB1);
            accFB[2] = bf_lo(pdB2) + bf_lo(psB2); accSB[2] = bf_hi(pdB2) + bf_hi(psB2);
            accFB[3] = bf_lo(pdB3) + bf_lo(psB3); accSB[3] = bf_hi(pdB3) + bf_hi(psB3);

            // ---- MFMA + activation + LDS write for both nt of the pair ----
            short8 bFA = BEv[ntA*64 + lane];
            short8 bSA = BEv[(ntA+8)*64 + lane];
            short8 bFB = BEv[ntB*64 + lane];
            short8 bSB = BEv[(ntB+8)*64 + lane];
            f32x4 qfA = __builtin_amdgcn_mfma_f32_16x16x32_bf16(a, bFA, accFA, 0, 0, 0);
            f32x4 qsA = __builtin_amdgcn_mfma_f32_16x16x32_bf16(a, bSA, accSA, 0, 0, 0);
            f32x4 qfB = __builtin_amdgcn_mfma_f32_16x16x32_bf16(a, bFB, accFB, 0, 0, 0);
            f32x4 qsB = __builtin_amdgcn_mfma_f32_16x16x32_bf16(a, bSB, accSB, 0, 0, 0);

            float4 mvA, mvB;
            #pragma unroll
            for (int r = 0; r < 4; ++r) {
                float sigA = __builtin_amdgcn_rcpf(1.0f + __builtin_amdgcn_exp2f(-qfA[r]));
                float spA  = __builtin_amdgcn_logf(1.0f + __builtin_amdgcn_exp2f(qsA[r]));
                ((float*)&mvA)[r] = sigA * spA;
                float sigB = __builtin_amdgcn_rcpf(1.0f + __builtin_amdgcn_exp2f(-qfB[r]));
                float spB  = __builtin_amdgcn_logf(1.0f + __builtin_amdgcn_exp2f(qsB[r]));
                ((float*)&mvB)[r] = sigB * spB;
            }
            const int rowA_ = (pair*2)*16 + m;       // channel row within this half
            const int rowB_ = (pair*2+1)*16 + m;
            *(float4*)&msgL[rowA_*68 + chunkp*4] = mvA;  // ds_write_b128
            *(float4*)&msgL[rowB_*68 + chunkp*4] = mvB;  // ds_write_b128
        }
        __syncthreads();

        // Segmented reduction: 256 threads = 64 channels x 4 segments of 16.
        // Interior runs -> plain store (unique writer); boundary runs -> atomic.
        {
            unsigned mfull = bmaskL[seg >> 1];
            unsigned msk = (unsigned)__builtin_amdgcn_readfirstlane(
                (int)((mfull >> ((seg & 1) * 16)) & 0xFFFEu));
            const int swz = 2*(c2 & 15);
            const float* rowp = &msgL[c2*68];
            float* aggc = agg + half*64 + c2;
            const int base = seg*16;
            float acc = 0.0f;
            bool inside = false;
            #pragma unroll
            for (int jj = 0; jj < 4; ++jj) {
                const int ch = seg*4 + jj;
                const float4 v4 = *(const float4*)&rowp[((ch + swz) & 15)*4];  // ds_read_b128
                #pragma unroll
                for (int k = 0; k < 4; ++k) {
                    if (msk & 1u) {
                        float* dp = &aggc[(size_t)pdL[base + jj*4 + k - 1] * HIDDEN];
                        if (inside) *dp = acc; else atomicAdd(dp, acc);
                        acc = 0.0f; inside = true;
                    }
                    msk >>= 1;
                    acc += ((const float*)&v4)[k];
                }
            }
            atomicAdd(&aggc[(size_t)pdL[base + 15] * HIDDEN], acc);
        }
        if (half == 0) __syncthreads();   // protect msgL reuse by phase 2
    }
}

// ---------------------------------------------------------------------------
// Pool with fused double update: h = relu(relu(H+ln2*agg1)+ln2*agg2).
// ---------------------------------------------------------------------------
__global__ __launch_bounds__(128) void pool_kernel(
    const float* __restrict__ H, const float* __restrict__ agg1,
    const float* __restrict__ agg2, const int* __restrict__ batch,
    float* __restrict__ gsum, float* __restrict__ gcnt)
{
    const int c = threadIdx.x;
    const int n0 = blockIdx.x * 32;
    float acc = 0.0f;
    int cur = -1;
    for (int i = 0; i < 32; ++i) {
        int n = n0 + i;
        if (n >= N_NODES) break;
        int g = batch[n];
        if (g != cur) {
            if (cur >= 0) atomicAdd(gsum + (size_t)cur * HIDDEN + c, acc);
            cur = g; acc = 0.0f;
        }
        size_t ix = (size_t)n * HIDDEN + c;
        float h = fmaxf(fmaf(agg2[ix], LN2, fmaxf(fmaf(agg1[ix], LN2, H[ix]), 0.0f)), 0.0f);
        acc += h;
    }
    if (cur >= 0) atomicAdd(gsum + (size_t)cur * HIDDEN + c, acc);

    if (c == 0) {
        int curg = -1; float run = 0.0f;
        for (int i = 0; i < 32; ++i) {
            int n = n0 + i;
            if (n >= N_NODES) break;
            int g = batch[n];
            if (g != curg) {
                if (curg >= 0) atomicAdd(gcnt + curg, run);
                curg = g; run = 0.0f;
            }
            run += 1.0f;
        }
        if (curg >= 0) atomicAdd(gcnt + curg, run);
    }
}

// ---------------------------------------------------------------------------
// Final MLP: g = relu((gsum/cnt) @ W1 + b1); out = g @ Wh^T + bh
// ---------------------------------------------------------------------------
__global__ __launch_bounds__(128) void head_kernel(
    const float* __restrict__ gsum, const float* __restrict__ gcnt,
    const float* __restrict__ W1, const float* __restrict__ b1,
    const float* __restrict__ Wh, const float* __restrict__ bh,
    float* __restrict__ out)
{
    __shared__ float gavg[128];
    __shared__ float g1[128];
    const int g = blockIdx.x, c = threadIdx.x;
    float cnt = fmaxf(gcnt[g], 1.0f);
    gavg[c] = gsum[(size_t)g * HIDDEN + c] / cnt;
    __syncthreads();
    float acc = b1[c];
    for (int k = 0; k < 128; ++k) acc += gavg[k] * W1[k*128 + c];
    g1[c] = fmaxf(acc, 0.0f);
    __syncthreads();
    if (c < 5) {
        float o = bh[c];
        for (int k = 0; k < 128; ++k) o += g1[k] * Wh[c*128 + k];
        out[(size_t)g * 5 + c] = o;
    }
}

// ---------------------------------------------------------------------------
// Launch
// ---------------------------------------------------------------------------
extern "C" void kernel_launch(void* const* d_in, const int* in_sizes, int n_in,
                              void* d_out, int out_size, void* d_ws, size_t ws_size,
                              hipStream_t stream) {
    const float* x        = (const float*)d_in[0];
    const int*   ei       = (const int*)  d_in[1];
    const float* EA       = (const float*)d_in[2];
    const int*   batch    = (const int*)  d_in[3];
    const float* Wf1      = (const float*)d_in[4];
    const float* bf1      = (const float*)d_in[5];
    const float* Ws1      = (const float*)d_in[6];
    const float* bs1      = (const float*)d_in[7];
    const float* Wp       = (const float*)d_in[8];
    const float* bp       = (const float*)d_in[9];
    const float* Wf_convs = (const float*)d_in[10];
    const float* bf_convs = (const float*)d_in[11];
    const float* Ws_convs = (const float*)d_in[12];
    const float* bs_convs = (const float*)d_in[13];
    const float* W1       = (const float*)d_in[14];
    const float* b1       = (const float*)d_in[15];
    const float* W_heads  = (const float*)d_in[16];
    const float* b_heads  = (const float*)d_in[17];
    float* out = (float*)d_out;

    float* ws = (float*)d_ws;
    // workspace layout (float units); agg1/agg2/agg0 contiguous for one memset
    float* H    = ws + 0;                                     // 6,400,000
    unsigned short* Pb = (unsigned short*)(ws + 6400000);     // 25.6M ushort
    float* agg1 = ws + 19200000;                              // 6,400,000
    float* agg2 = ws + 25600000;                              // 6,400,000
    float* agg0 = ws + 32000000;                              // 150,016
    unsigned short* Bfrag = (unsigned short*)(ws + 32150016); // 131072 ushort
    unsigned short* BE    = (unsigned short*)(ws + 32215552); // 16384 ushort
    float* gsum = ws + 32223744;                              // 32768
    float* gcnt = ws + 32256512;                              // 512
    int* hist   = (int*)(ws + 32257024);                      // NPAD
    int* cursor = (int*)(ws + 32307200);                      // NPAD
    int* btot   = (int*)(ws + 32357376);                      // 256
    int4* epack = (int4*)(ws + 32357632);                     // 800000 int4 = 3.2M floats
    unsigned short* EAb = (unsigned short*)(ws + 35557632);   // 25.6M ushort (optional)
    const size_t need_eab = (size_t)(35557632 + 12800000) * 4;
    unsigned short* EAb_use = (ws_size >= need_eab) ? EAb : (unsigned short*)nullptr;
    // rank parks in the Pb region: produced by hist, consumed by scatter,
    // then Pb is fully overwritten by gemm0 (first Pb producer).
    int* rank = (int*)Pb;

    // ---- upfront memsets ----
    hipMemsetAsync(hist, 0, (size_t)NPAD * sizeof(int), stream);
    hipMemsetAsync(agg1, 0, (size_t)(2 * N_NODES * HIDDEN + 150016) * sizeof(float), stream);
    hipMemsetAsync(gsum, 0, (size_t)(NUM_GRAPHS * HIDDEN + NUM_GRAPHS) * sizeof(float), stream);

    // ---- edge sort by dst (hist fused with weight repack; rank recorded) ----
    hist_repack_kernel<<<(N_EDGES + 255)/256, 256, 0, stream>>>(
        ei, hist, rank, Wf_convs, Ws_convs, Bfrag, BE);
    scanA_kernel<<<NPAD/256, 256, 0, stream>>>(hist, cursor, btot);
    scanB_kernel<<<1, 256, 0, stream>>>(btot);
    scatter_kernel<<<(N_EDGES + 255)/256, 256, 0, stream>>>(ei, cursor, btot, rank, epack);

    // conv1 (dst-sorted, log2-domain, emits sorted bf16 EA)
    conv1_sorted_kernel<<<N_EDGES/256, 256, 0, stream>>>(
        x, EA, epack, Wf1, bf1, Ws1, bs1, agg0, EAb_use);

    dim3 ggrid(2, (N_NODES + 63)/64);
    // ---- layer 0: proj fused into gemm; A = relu(bp + (x+ln2*agg0)@Wp) ----
    gemm0_fused_kernel<<<ggrid, 256, 0, stream>>>(
        x, agg0, Wp, bp, Bfrag, bf_convs, bs_convs, Pb, H);
    edge_kernel<<<N_EDGES/64, 256, 0, stream>>>(Pb, EA, EAb_use, epack, BE, agg1);
    // ---- layer 1: A = relu(H + ln2*agg1), fused ----
    gemm_mfma<<<ggrid, 256, 0, stream>>>(H, agg1, Bfrag + (size_t)32*4*64*8,
                                         bf_convs + HIDDEN, bs_convs + HIDDEN, Pb);
    edge_kernel<<<N_EDGES/64, 256, 0, stream>>>(Pb, EA, EAb_use, epack,
                                                BE + (size_t)16*64*8, agg2);

    // pool (fused relu(relu(H+ln2*agg1)+ln2*agg2)) + heads
    pool_kernel<<<(N_NODES + 31)/32, 128, 0, stream>>>(H, agg1, agg2, batch, gsum, gcnt);
    head_kernel<<<NUM_GRAPHS, 128, 0, stream>>>(gsum, gcnt, W1, b1, W_heads, b_heads, out);
}

// Round 12
// 581.148 us; speedup vs baseline: 1.1067x; 1.1067x over previous
//
#include <hip/hip_runtime.h>
#include <hip/hip_bf16.h>
#include <math.h>

// Problem constants (fixed by the reference)
#define N_NODES 50000
#define N_EDGES 800000
#define NODE_DIM 3
#define EDGE_DIM 32
#define HIDDEN 128
#define NUM_GRAPHS 256
#define ZIN (2*HIDDEN + EDGE_DIM)   // 288
#define NPAD 50176                  // 196 * 256 (padded node count for scan)

#define LOG2E 1.44269504088896f
#define LN2   0.69314718055995f

typedef __attribute__((ext_vector_type(8))) short short8;
typedef __attribute__((ext_vector_type(4))) float f32x4;

// fp32 -> bf16 (RNE), finite inputs
__device__ __forceinline__ unsigned short f2bf(float x) {
    unsigned u = __float_as_uint(x);
    u += 0x7FFFu + ((u >> 16) & 1u);
    return (unsigned short)(u >> 16);
}
// low/high bf16 of a packed uint -> fp32
__device__ __forceinline__ float bf_lo(unsigned u) { return __uint_as_float(u << 16); }
__device__ __forceinline__ float bf_hi(unsigned u) { return __uint_as_float(u & 0xFFFF0000u); }

// ---------------------------------------------------------------------------
// conv1 (dst-sorted + log2-domain). Also emits EAb: bf16 edge attrs in
// SORTED order (64 B/edge) so the edge kernels read them coalesced with no
// eid indirection. Numerically identical (same f2bf of same fp32 values).
// ---------------------------------------------------------------------------
__global__ __launch_bounds__(256) void conv1_sorted_kernel(
    const float* __restrict__ x, const float* __restrict__ EA,
    const int4* __restrict__ epack,
    const float* __restrict__ Wf1, const float* __restrict__ bf1,
    const float* __restrict__ Ws1, const float* __restrict__ bs1,
    float* __restrict__ agg0, unsigned short* __restrict__ EAb)
{
    __shared__ float WfL[38*3], WsL[38*3], bfL[3], bsL[3];
    __shared__ float msgL[256*5];   // [edge][ch], stride 5 (conflict-free)
    __shared__ int   pdL[256];

    if (threadIdx.x < 114) {
        WfL[threadIdx.x] = Wf1[threadIdx.x] * LOG2E;
        WsL[threadIdx.x] = Ws1[threadIdx.x] * LOG2E;
    }
    if (threadIdx.x < 3) {
        bfL[threadIdx.x] = bf1[threadIdx.x] * LOG2E;
        bsL[threadIdx.x] = bs1[threadIdx.x] * LOG2E;
    }
    __syncthreads();

    const int p = blockIdx.x * 256 + threadIdx.x;   // 800000 % 256 == 0
    int4 e = epack[p];
    const int eid = e.x, s = e.y, d = e.z;
    pdL[threadIdx.x] = d;

    float z[38];
    z[0] = x[d*3+0]; z[1] = x[d*3+1]; z[2] = x[d*3+2];
    z[3] = x[s*3+0]; z[4] = x[s*3+1]; z[5] = x[s*3+2];
    const float4* ep = (const float4*)(EA + (size_t)eid * EDGE_DIM);
    #pragma unroll
    for (int q = 0; q < 8; ++q) {
        float4 v = ep[q];
        z[6+4*q+0] = v.x; z[6+4*q+1] = v.y; z[6+4*q+2] = v.z; z[6+4*q+3] = v.w;
    }

    if (EAb) {   // uniform branch: emit sorted bf16 edge attrs
        unsigned short vals[32];
        #pragma unroll
        for (int j = 0; j < 32; ++j) vals[j] = f2bf(z[6+j]);
        unsigned short* dst = EAb + (size_t)p * 32;
        *(short8*)(dst + 0)  = *(short8*)(vals + 0);
        *(short8*)(dst + 8)  = *(short8*)(vals + 8);
        *(short8*)(dst + 16) = *(short8*)(vals + 16);
        *(short8*)(dst + 24) = *(short8*)(vals + 24);
    }

    float f[3], g[3];
    #pragma unroll
    for (int c = 0; c < 3; ++c) { f[c] = bfL[c]; g[c] = bsL[c]; }
    #pragma unroll
    for (int j = 0; j < 38; ++j) {
        #pragma unroll
        for (int c = 0; c < 3; ++c) {
            f[c] += z[j] * WfL[j*3+c];
            g[c] += z[j] * WsL[j*3+c];
        }
    }
    #pragma unroll
    for (int c = 0; c < 3; ++c) {
        float sig = __builtin_amdgcn_rcpf(1.0f + __builtin_amdgcn_exp2f(-f[c]));
        float sp  = __builtin_amdgcn_logf(1.0f + __builtin_amdgcn_exp2f(g[c]));
        msgL[threadIdx.x*5 + c] = sig * sp;
    }
    __syncthreads();

    // Segmented reduction: 48 threads = 3 channels x 16 segments of 16 edges.
    if (threadIdx.x < 48) {
        const int c   = threadIdx.x % 3;
        const int seg = threadIdx.x / 3;
        const int base = seg * 16;
        float acc = 0.0f;
        int cur = pdL[base];
        #pragma unroll 4
        for (int i = 0; i < 16; ++i) {
            int dd = pdL[base + i];
            float v = msgL[(base + i)*5 + c];
            if (dd != cur) {
                atomicAdd(agg0 + (size_t)cur*3 + c, acc);
                acc = 0.0f; cur = dd;
            }
            acc += v;
        }
        atomicAdd(agg0 + (size_t)cur*3 + c, acc);
    }
}

// ---------------------------------------------------------------------------
// hist + weight repack fused. Stores rank[e] (the atomicAdd return) so
// scatter needs no atomics; rank parks in the Pb region (overwritten later).
// ---------------------------------------------------------------------------
__global__ __launch_bounds__(256) void hist_repack_kernel(
    const int* __restrict__ ei, int* __restrict__ hist, int* __restrict__ rank,
    const float* __restrict__ Wf, const float* __restrict__ Ws,
    unsigned short* __restrict__ Bfrag, unsigned short* __restrict__ BE)
{
    int e = blockIdx.x * 256 + threadIdx.x;
    if (e < N_EDGES) rank[e] = atomicAdd(&hist[ei[N_EDGES + e]], 1);

    int idx = e;
    if (idx < 2*32*4*64) {          // node-path: 16384 frags
        int lane = idx & 63;
        int kc   = (idx >> 6) & 3;
        int nt   = (idx >> 8) & 31;
        int l    = idx >> 13;
        const float* wf  = Wf + (size_t)l * ZIN * HIDDEN;
        const float* wsp = Ws + (size_t)l * ZIN * HIDDEN;
        int n = nt*16 + (lane & 15);
        int half = n >> 8;
        int within = n & 255;
        int cc = within >> 1;
        int t = within & 1;
        const float* W = t ? wsp : wf;
        unsigned short vals[8];
        #pragma unroll
        for (int j = 0; j < 8; ++j) {
            int k = kc*32 + (lane >> 4)*8 + j;
            vals[j] = f2bf(W[(size_t)(half*128 + k)*128 + cc] * LOG2E);
        }
        *(short8*)(Bfrag + (size_t)idx * 8) = *(short8*)vals;
    } else if (idx < 2*32*4*64 + 2*16*64) {   // edge-path: 2048 frags
        int i2 = idx - 2*32*4*64;
        int lane = i2 & 63;
        int nt   = (i2 >> 6) & 15;
        int l    = i2 >> 10;
        const float* W = ((nt & 8) ? Ws : Wf) + (size_t)l * ZIN * HIDDEN + 256*128;
        int c = (nt & 7)*16 + (lane & 15);
        unsigned short vals[8];
        #pragma unroll
        for (int j = 0; j < 8; ++j) {
            int k = (lane >> 4)*8 + j;
            vals[j] = f2bf(W[(size_t)k*128 + c] * LOG2E);
        }
        *(short8*)(BE + (size_t)i2 * 8) = *(short8*)vals;
    }
}

__global__ __launch_bounds__(256) void scanA_kernel(
    const int* __restrict__ hist, int* __restrict__ cursor, int* __restrict__ btot)
{
    __shared__ int tmp[256];
    int t = threadIdx.x;
    int i = blockIdx.x * 256 + t;
    int v = hist[i];
    tmp[t] = v;
    __syncthreads();
    #pragma unroll
    for (int off = 1; off < 256; off <<= 1) {
        int y = (t >= off) ? tmp[t - off] : 0;
        __syncthreads();
        if (t >= off) tmp[t] += y;
        __syncthreads();
    }
    cursor[i] = tmp[t] - v;
    if (t == 255) btot[blockIdx.x] = tmp[t];
}

__global__ __launch_bounds__(256) void scanB_kernel(int* __restrict__ btot)
{
    __shared__ int tmp[256];
    int t = threadIdx.x;
    int v = btot[t];
    tmp[t] = v;
    __syncthreads();
    #pragma unroll
    for (int off = 1; off < 256; off <<= 1) {
        int y = (t >= off) ? tmp[t - off] : 0;
        __syncthreads();
        if (t >= off) tmp[t] += y;
        __syncthreads();
    }
    btot[t] = tmp[t] - v;
}

// Scatter: one int4 store per edge (eid, src, dst, 0) at its sorted slot.
// slot = cursor[d] + rank[e] + btot[d>>8] -- no atomics, deterministic.
__global__ __launch_bounds__(256) void scatter_kernel(
    const int* __restrict__ ei, const int* __restrict__ cursor,
    const int* __restrict__ btot, const int* __restrict__ rank,
    int4* __restrict__ epack)
{
    int e = blockIdx.x * 256 + threadIdx.x;
    if (e >= N_EDGES) return;
    int s = ei[e];
    int d = ei[N_EDGES + e];
    int p = cursor[d] + rank[e] + btot[d >> 8];
    epack[p] = make_int4(e, s, d, 0);
}

// ---------------------------------------------------------------------------
// gemm0 with proj fused: A-row = relu(bp + (x+ln2*agg0)@Wp), computed
// in-block from the 3-dim inputs (Wp/bp in LDS); H stored once (colBase==0).
// Then Pb = bf16(A @ (log2e*Wcat) + log2e*bias) as before.
// ---------------------------------------------------------------------------
__global__ __launch_bounds__(256) void gemm0_fused_kernel(
    const float* __restrict__ x, const float* __restrict__ agg0,
    const float* __restrict__ Wp, const float* __restrict__ bp,
    const unsigned short* __restrict__ Bfrag,
    const float* __restrict__ bf, const float* __restrict__ bs,
    unsigned short* __restrict__ Pb, float* __restrict__ H)
{
    __shared__ float WpL[384], bpL[128];
    WpL[threadIdx.x] = Wp[threadIdx.x];
    if (threadIdx.x < 128) {
        WpL[256 + threadIdx.x] = Wp[256 + threadIdx.x];
        bpL[threadIdx.x] = bp[threadIdx.x];
    }
    __syncthreads();

    const int lane = threadIdx.x & 63;
    const int wave = threadIdx.x >> 6;
    const int m    = lane & 15;
    const int quad = lane >> 4;
    const int rowA = blockIdx.y * 64 + wave * 16 + m;
    const int rowX = rowA < N_NODES ? rowA : N_NODES - 1;   // clamp input reads
    const int colBase = blockIdx.x * 256;

    float h0 = fmaf(agg0[rowX*3+0], LN2, x[rowX*3+0]);
    float h1 = fmaf(agg0[rowX*3+1], LN2, x[rowX*3+1]);
    float h2 = fmaf(agg0[rowX*3+2], LN2, x[rowX*3+2]);

    short8 a[4];
    #pragma unroll
    for (int kc = 0; kc < 4; ++kc) {
        float vv[8];
        unsigned short t[8];
        #pragma unroll
        for (int i = 0; i < 8; ++i) {
            int col = kc*32 + quad*8 + i;
            float v = bpL[col] + h0*WpL[col] + h1*WpL[128+col] + h2*WpL[256+col];
            v = fmaxf(v, 0.0f);
            vv[i] = v;
            t[i] = f2bf(v);
        }
        a[kc] = *(short8*)t;
        if (colBase == 0 && rowA < N_NODES) {
            float* hp = H + (size_t)rowA * 128 + kc*32 + quad*8;
            *(float4*)hp       = make_float4(vv[0], vv[1], vv[2], vv[3]);
            *(float4*)(hp + 4) = make_float4(vv[4], vv[5], vv[6], vv[7]);
        }
    }

    f32x4 acc[16];
    #pragma unroll
    for (int nt = 0; nt < 16; ++nt) {
        float bias = 0.0f;
        if (colBase == 0) {
            int col = nt*16 + m;
            bias = ((col & 1) ? bs[col >> 1] : bf[col >> 1]) * LOG2E;
        }
        acc[nt] = (f32x4){bias, bias, bias, bias};
    }

    #pragma unroll
    for (int nt = 0; nt < 16; ++nt) {
        int ntg = (colBase >> 4) + nt;
        const unsigned short* bpf = Bfrag + ((size_t)(ntg*4) * 64 + lane) * 8;
        #pragma unroll
        for (int kc = 0; kc < 4; ++kc) {
            short8 b = *(const short8*)(bpf + (size_t)kc * 64 * 8);
            acc[nt] = __builtin_amdgcn_mfma_f32_16x16x32_bf16(a[kc], b, acc[nt], 0, 0, 0);
        }
    }

    const int rowC = blockIdx.y * 64 + wave * 16 + quad * 4;
    #pragma unroll
    for (int nt = 0; nt < 16; ++nt) {
        int col = colBase + nt*16 + m;
        #pragma unroll
        for (int r = 0; r < 4; ++r) {
            int row = rowC + r;
            if (row < N_NODES) Pb[(size_t)row * 512 + col] = f2bf(acc[nt][r]);
        }
    }
}

// ---------------------------------------------------------------------------
// Node MFMA GEMM (layer 1): A = relu(H + ln2*aggIn), fused into the A-load.
// ---------------------------------------------------------------------------
__global__ __launch_bounds__(256) void gemm_mfma(
    const float* __restrict__ H, const float* __restrict__ aggIn,
    const unsigned short* __restrict__ Bfrag,
    const float* __restrict__ bf, const float* __restrict__ bs,
    unsigned short* __restrict__ Pb)
{
    const int lane = threadIdx.x & 63;
    const int wave = threadIdx.x >> 6;
    const int m    = lane & 15;
    const int quad = lane >> 4;
    const int rowA = blockIdx.y * 64 + wave * 16 + m;   // OOB rows read ws (safe); stores masked
    const int colBase = blockIdx.x * 256;

    const float* hrow = H + (size_t)rowA * 128;
    const float* arow = aggIn + (size_t)rowA * 128;
    short8 a[4];
    #pragma unroll
    for (int kc = 0; kc < 4; ++kc) {
        float4 v0 = *(const float4*)(hrow + kc*32 + quad*8);
        float4 v1 = *(const float4*)(hrow + kc*32 + quad*8 + 4);
        float4 a0 = *(const float4*)(arow + kc*32 + quad*8);
        float4 a1 = *(const float4*)(arow + kc*32 + quad*8 + 4);
        v0.x = fmaxf(fmaf(a0.x, LN2, v0.x), 0.f); v0.y = fmaxf(fmaf(a0.y, LN2, v0.y), 0.f);
        v0.z = fmaxf(fmaf(a0.z, LN2, v0.z), 0.f); v0.w = fmaxf(fmaf(a0.w, LN2, v0.w), 0.f);
        v1.x = fmaxf(fmaf(a1.x, LN2, v1.x), 0.f); v1.y = fmaxf(fmaf(a1.y, LN2, v1.y), 0.f);
        v1.z = fmaxf(fmaf(a1.z, LN2, v1.z), 0.f); v1.w = fmaxf(fmaf(a1.w, LN2, v1.w), 0.f);
        unsigned short t[8];
        t[0]=f2bf(v0.x); t[1]=f2bf(v0.y); t[2]=f2bf(v0.z); t[3]=f2bf(v0.w);
        t[4]=f2bf(v1.x); t[5]=f2bf(v1.y); t[6]=f2bf(v1.z); t[7]=f2bf(v1.w);
        a[kc] = *(short8*)t;
    }

    f32x4 acc[16];
    #pragma unroll
    for (int nt = 0; nt < 16; ++nt) {
        float bias = 0.0f;
        if (colBase == 0) {
            int col = nt*16 + m;
            bias = ((col & 1) ? bs[col >> 1] : bf[col >> 1]) * LOG2E;
        }
        acc[nt] = (f32x4){bias, bias, bias, bias};
    }

    #pragma unroll
    for (int nt = 0; nt < 16; ++nt) {
        int ntg = (colBase >> 4) + nt;
        const unsigned short* bp = Bfrag + ((size_t)(ntg*4) * 64 + lane) * 8;
        #pragma unroll
        for (int kc = 0; kc < 4; ++kc) {
            short8 b = *(const short8*)(bp + (size_t)kc * 64 * 8);
            acc[nt] = __builtin_amdgcn_mfma_f32_16x16x32_bf16(a[kc], b, acc[nt], 0, 0, 0);
        }
    }

    const int rowC = blockIdx.y * 64 + wave * 16 + quad * 4;
    #pragma unroll
    for (int nt = 0; nt < 16; ++nt) {
        int col = colBase + nt*16 + m;
        #pragma unroll
        for (int r = 0; r < 4; ++r) {
            int row = rowC + r;
            if (row < N_NODES) Pb[(size_t)row * 512 + col] = f2bf(acc[nt][r]);
        }
    }
}

// ---------------------------------------------------------------------------
// Fused edge kernel, v14 (reverted exactly to the R7-measured form, the best
// stable variant: 98 us, FETCH 220 MB, WRITE 48.5 MB). Gather-ILP batching
// abandoned: R8 spilled, R9 was rescheduled away, R10's pin spilled again --
// the kernel is at its coherent-gather floor for this structure.
// ---------------------------------------------------------------------------
__global__ __launch_bounds__(256, 8) void edge_kernel(
    const unsigned short* __restrict__ Pb, const float* __restrict__ EA,
    const unsigned short* __restrict__ EAb,
    const int4* __restrict__ epack,
    const unsigned short* __restrict__ BE,
    float* __restrict__ agg)
{
    __shared__ float msgL[64*68];           // 17.4 KB, [c-row][swizzled 4-edge chunks]
    __shared__ int pdL[64];
    __shared__ unsigned bmaskL[2];

    if (threadIdx.x < 64) {
        const int t = threadIdx.x;
        int d = epack[blockIdx.x*64 + t].z;
        pdL[t] = d;
        bool b = (t & 15) ? (d != pdL[t-1]) : false;   // zero bits 0,16,32,48 (seg starts)
        unsigned long long bal = __ballot(b);
        if (t == 0) { bmaskL[0] = (unsigned)bal; bmaskL[1] = (unsigned)(bal >> 32); }
    }

    const int lane = threadIdx.x & 63;
    const int wave = threadIdx.x >> 6;
    const int m    = lane & 15;
    const int quad = lane >> 4;
    const int p0   = blockIdx.x * 64 + wave * 16;   // 800000 % 64 == 0

    // A-frag: this lane's edge attrs (bf16)
    short8 a;
    if (EAb) {   // direct coalesced load, address known at entry
        a = *(const short8*)(EAb + (size_t)(p0 + m) * 32 + quad*8);
    } else {
        int eid = epack[p0 + m].x;
        const float* ea = EA + (size_t)eid * EDGE_DIM + quad*8;
        float4 v0 = *(const float4*)ea;
        float4 v1 = *(const float4*)(ea + 4);
        unsigned short t[8];
        t[0]=f2bf(v0.x); t[1]=f2bf(v0.y); t[2]=f2bf(v0.z); t[3]=f2bf(v0.w);
        t[4]=f2bf(v1.x); t[5]=f2bf(v1.y); t[6]=f2bf(v1.z); t[7]=f2bf(v1.w);
        a = *(short8*)t;
    }

    // Per-r base pointers: nt offsets become compile-time immediates.
    const unsigned short* pdp[4];
    const unsigned short* psp[4];
    #pragma unroll
    for (int r = 0; r < 4; ++r) {
        int4 e = epack[p0 + quad*4 + r];
        pdp[r] = Pb + (size_t)e.z * 512 + 2*m;
        psp[r] = Pb + (size_t)e.y * 512 + 256 + 2*m;
    }

    const short8* BEv = (const short8*)BE;   // 16 KB, L1-resident
    const int chunk  = wave*4 + quad;        // this thread's 4-edge chunk (0..15)
    const int c2  = threadIdx.x & 63;        // reduce: channel row
    const int seg = threadIdx.x >> 6;        // reduce: 16-edge segment (== wave)

    #pragma unroll
    for (int half = 0; half < 2; ++half) {
        #pragma unroll
        for (int nt4 = 0; nt4 < 4; ++nt4) {
            const int nt = half*4 + nt4;
            short8 bF = BEv[nt*64 + lane];
            short8 bS = BEv[(nt+8)*64 + lane];
            // gather sums preloaded into the MFMA accumulator
            f32x4 accF, accS;
            #pragma unroll
            for (int r = 0; r < 4; ++r) {
                unsigned pd = *(const unsigned*)(pdp[r] + nt*32);
                unsigned ps = *(const unsigned*)(psp[r] + nt*32);
                accF[r] = bf_lo(pd) + bf_lo(ps);
                accS[r] = bf_hi(pd) + bf_hi(ps);
            }
            f32x4 qf = __builtin_amdgcn_mfma_f32_16x16x32_bf16(a, bF, accF, 0, 0, 0);
            f32x4 qs = __builtin_amdgcn_mfma_f32_16x16x32_bf16(a, bS, accS, 0, 0, 0);
            float4 mv;
            #pragma unroll
            for (int r = 0; r < 4; ++r) {
                float sig = __builtin_amdgcn_rcpf(1.0f + __builtin_amdgcn_exp2f(-qf[r]));
                float sp  = __builtin_amdgcn_logf(1.0f + __builtin_amdgcn_exp2f(qs[r]));
                ((float*)&mv)[r] = sig * sp;
            }
            const int row = nt4*16 + m;               // channel row within this half
            const int chunkp = (chunk + 2*m) & 15;    // rotate-swizzle
            *(float4*)&msgL[row*68 + chunkp*4] = mv;  // ds_write_b128
        }
        __syncthreads();

        // Segmented reduction: 256 threads = 64 channels x 4 segments of 16.
        // Interior runs -> plain store (unique writer); boundary runs -> atomic.
        {
            unsigned mfull = bmaskL[seg >> 1];
            unsigned msk = (unsigned)__builtin_amdgcn_readfirstlane(
                (int)((mfull >> ((seg & 1) * 16)) & 0xFFFEu));
            const int swz = 2*(c2 & 15);
            const float* rowp = &msgL[c2*68];
            float* aggc = agg + half*64 + c2;
            const int base = seg*16;
            float acc = 0.0f;
            bool inside = false;
            #pragma unroll
            for (int jj = 0; jj < 4; ++jj) {
                const int ch = seg*4 + jj;
                const float4 v4 = *(const float4*)&rowp[((ch + swz) & 15)*4];  // ds_read_b128
                #pragma unroll
                for (int k = 0; k < 4; ++k) {
                    if (msk & 1u) {
                        float* dp = &aggc[(size_t)pdL[base + jj*4 + k - 1] * HIDDEN];
                        if (inside) *dp = acc; else atomicAdd(dp, acc);
                        acc = 0.0f; inside = true;
                    }
                    msk >>= 1;
                    acc += ((const float*)&v4)[k];
                }
            }
            atomicAdd(&aggc[(size_t)pdL[base + 15] * HIDDEN], acc);
        }
        if (half == 0) __syncthreads();   // protect msgL reuse by phase 2
    }
}

// ---------------------------------------------------------------------------
// Pool with fused double update: h = relu(relu(H+ln2*agg1)+ln2*agg2).
// ---------------------------------------------------------------------------
__global__ __launch_bounds__(128) void pool_kernel(
    const float* __restrict__ H, const float* __restrict__ agg1,
    const float* __restrict__ agg2, const int* __restrict__ batch,
    float* __restrict__ gsum, float* __restrict__ gcnt)
{
    const int c = threadIdx.x;
    const int n0 = blockIdx.x * 32;
    float acc = 0.0f;
    int cur = -1;
    for (int i = 0; i < 32; ++i) {
        int n = n0 + i;
        if (n >= N_NODES) break;
        int g = batch[n];
        if (g != cur) {
            if (cur >= 0) atomicAdd(gsum + (size_t)cur * HIDDEN + c, acc);
            cur = g; acc = 0.0f;
        }
        size_t ix = (size_t)n * HIDDEN + c;
        float h = fmaxf(fmaf(agg2[ix], LN2, fmaxf(fmaf(agg1[ix], LN2, H[ix]), 0.0f)), 0.0f);
        acc += h;
    }
    if (cur >= 0) atomicAdd(gsum + (size_t)cur * HIDDEN + c, acc);

    if (c == 0) {
        int curg = -1; float run = 0.0f;
        for (int i = 0; i < 32; ++i) {
            int n = n0 + i;
            if (n >= N_NODES) break;
            int g = batch[n];
            if (g != curg) {
                if (curg >= 0) atomicAdd(gcnt + curg, run);
                curg = g; run = 0.0f;
            }
            run += 1.0f;
        }
        if (curg >= 0) atomicAdd(gcnt + curg, run);
    }
}

// ---------------------------------------------------------------------------
// Final MLP: g = relu((gsum/cnt) @ W1 + b1); out = g @ Wh^T + bh
// ---------------------------------------------------------------------------
__global__ __launch_bounds__(128) void head_kernel(
    const float* __restrict__ gsum, const float* __restrict__ gcnt,
    const float* __restrict__ W1, const float* __restrict__ b1,
    const float* __restrict__ Wh, const float* __restrict__ bh,
    float* __restrict__ out)
{
    __shared__ float gavg[128];
    __shared__ float g1[128];
    const int g = blockIdx.x, c = threadIdx.x;
    float cnt = fmaxf(gcnt[g], 1.0f);
    gavg[c] = gsum[(size_t)g * HIDDEN + c] / cnt;
    __syncthreads();
    float acc = b1[c];
    for (int k = 0; k < 128; ++k) acc += gavg[k] * W1[k*128 + c];
    g1[c] = fmaxf(acc, 0.0f);
    __syncthreads();
    if (c < 5) {
        float o = bh[c];
        for (int k = 0; k < 128; ++k) o += g1[k] * Wh[c*128 + k];
        out[(size_t)g * 5 + c] = o;
    }
}

// ---------------------------------------------------------------------------
// Launch
// ---------------------------------------------------------------------------
extern "C" void kernel_launch(void* const* d_in, const int* in_sizes, int n_in,
                              void* d_out, int out_size, void* d_ws, size_t ws_size,
                              hipStream_t stream) {
    const float* x        = (const float*)d_in[0];
    const int*   ei       = (const int*)  d_in[1];
    const float* EA       = (const float*)d_in[2];
    const int*   batch    = (const int*)  d_in[3];
    const float* Wf1      = (const float*)d_in[4];
    const float* bf1      = (const float*)d_in[5];
    const float* Ws1      = (const float*)d_in[6];
    const float* bs1      = (const float*)d_in[7];
    const float* Wp       = (const float*)d_in[8];
    const float* bp       = (const float*)d_in[9];
    const float* Wf_convs = (const float*)d_in[10];
    const float* bf_convs = (const float*)d_in[11];
    const float* Ws_convs = (const float*)d_in[12];
    const float* bs_convs = (const float*)d_in[13];
    const float* W1       = (const float*)d_in[14];
    const float* b1       = (const float*)d_in[15];
    const float* W_heads  = (const float*)d_in[16];
    const float* b_heads  = (const float*)d_in[17];
    float* out = (float*)d_out;

    float* ws = (float*)d_ws;
    // workspace layout (float units); agg1/agg2/agg0 contiguous for one memset
    float* H    = ws + 0;                                     // 6,400,000
    unsigned short* Pb = (unsigned short*)(ws + 6400000);     // 25.6M ushort
    float* agg1 = ws + 19200000;                              // 6,400,000
    float* agg2 = ws + 25600000;                              // 6,400,000
    float* agg0 = ws + 32000000;                              // 150,016
    unsigned short* Bfrag = (unsigned short*)(ws + 32150016); // 131072 ushort
    unsigned short* BE    = (unsigned short*)(ws + 32215552); // 16384 ushort
    float* gsum = ws + 32223744;                              // 32768
    float* gcnt = ws + 32256512;                              // 512
    int* hist   = (int*)(ws + 32257024);                      // NPAD
    int* cursor = (int*)(ws + 32307200);                      // NPAD
    int* btot   = (int*)(ws + 32357376);                      // 256
    int4* epack = (int4*)(ws + 32357632);                     // 800000 int4 = 3.2M floats
    unsigned short* EAb = (unsigned short*)(ws + 35557632);   // 25.6M ushort (optional)
    const size_t need_eab = (size_t)(35557632 + 12800000) * 4;
    unsigned short* EAb_use = (ws_size >= need_eab) ? EAb : (unsigned short*)nullptr;
    // rank parks in the Pb region: produced by hist, consumed by scatter,
    // then Pb is fully overwritten by gemm0 (first Pb producer).
    int* rank = (int*)Pb;

    // ---- upfront memsets ----
    hipMemsetAsync(hist, 0, (size_t)NPAD * sizeof(int), stream);
    hipMemsetAsync(agg1, 0, (size_t)(2 * N_NODES * HIDDEN + 150016) * sizeof(float), stream);
    hipMemsetAsync(gsum, 0, (size_t)(NUM_GRAPHS * HIDDEN + NUM_GRAPHS) * sizeof(float), stream);

    // ---- edge sort by dst (hist fused with weight repack; rank recorded) ----
    hist_repack_kernel<<<(N_EDGES + 255)/256, 256, 0, stream>>>(
        ei, hist, rank, Wf_convs, Ws_convs, Bfrag, BE);
    scanA_kernel<<<NPAD/256, 256, 0, stream>>>(hist, cursor, btot);
    scanB_kernel<<<1, 256, 0, stream>>>(btot);
    scatter_kernel<<<(N_EDGES + 255)/256, 256, 0, stream>>>(ei, cursor, btot, rank, epack);

    // conv1 (dst-sorted, log2-domain, emits sorted bf16 EA)
    conv1_sorted_kernel<<<N_EDGES/256, 256, 0, stream>>>(
        x, EA, epack, Wf1, bf1, Ws1, bs1, agg0, EAb_use);

    dim3 ggrid(2, (N_NODES + 63)/64);
    // ---- layer 0: proj fused into gemm; A = relu(bp + (x+ln2*agg0)@Wp) ----
    gemm0_fused_kernel<<<ggrid, 256, 0, stream>>>(
        x, agg0, Wp, bp, Bfrag, bf_convs, bs_convs, Pb, H);
    edge_kernel<<<N_EDGES/64, 256, 0, stream>>>(Pb, EA, EAb_use, epack, BE, agg1);
    // ---- layer 1: A = relu(H + ln2*agg1), fused ----
    gemm_mfma<<<ggrid, 256, 0, stream>>>(H, agg1, Bfrag + (size_t)32*4*64*8,
                                         bf_convs + HIDDEN, bs_convs + HIDDEN, Pb);
    edge_kernel<<<N_EDGES/64, 256, 0, stream>>>(Pb, EA, EAb_use, epack,
                                                BE + (size_t)16*64*8, agg2);

    // pool (fused relu(relu(H+ln2*agg1)+ln2*agg2)) + heads
    pool_kernel<<<(N_NODES + 31)/32, 128, 0, stream>>>(H, agg1, agg2, batch, gsum, gcnt);
    head_kernel<<<NUM_GRAPHS, 128, 0, stream>>>(gsum, gcnt, W1, b1, W_heads, b_heads, out);
}

// Round 13
// 566.753 us; speedup vs baseline: 1.1349x; 1.0254x over previous
//
#include <hip/hip_runtime.h>
#include <hip/hip_bf16.h>
#include <math.h>

// Problem constants (fixed by the reference)
#define N_NODES 50000
#define N_EDGES 800000
#define NODE_DIM 3
#define EDGE_DIM 32
#define HIDDEN 128
#define NUM_GRAPHS 256
#define ZIN (2*HIDDEN + EDGE_DIM)   // 288
#define NPAD 50176                  // 196 * 256 (padded node count for scan)

#define LOG2E 1.44269504088896f
#define LN2   0.69314718055995f

typedef __attribute__((ext_vector_type(8))) short short8;
typedef __attribute__((ext_vector_type(4))) float f32x4;

// fp32 -> bf16 (RNE), finite inputs
__device__ __forceinline__ unsigned short f2bf(float x) {
    unsigned u = __float_as_uint(x);
    u += 0x7FFFu + ((u >> 16) & 1u);
    return (unsigned short)(u >> 16);
}
// low/high bf16 of a packed uint -> fp32
__device__ __forceinline__ float bf_lo(unsigned u) { return __uint_as_float(u << 16); }
__device__ __forceinline__ float bf_hi(unsigned u) { return __uint_as_float(u & 0xFFFF0000u); }

// ---------------------------------------------------------------------------
// conv1 (dst-sorted + log2-domain). Also emits EAb: bf16 edge attrs in
// SORTED order (64 B/edge) so the edge kernels read them coalesced with no
// eid indirection. Numerically identical (same f2bf of same fp32 values).
// ---------------------------------------------------------------------------
__global__ __launch_bounds__(256) void conv1_sorted_kernel(
    const float* __restrict__ x, const float* __restrict__ EA,
    const int4* __restrict__ epack,
    const float* __restrict__ Wf1, const float* __restrict__ bf1,
    const float* __restrict__ Ws1, const float* __restrict__ bs1,
    float* __restrict__ agg0, unsigned short* __restrict__ EAb)
{
    __shared__ float WfL[38*3], WsL[38*3], bfL[3], bsL[3];
    __shared__ float msgL[256*5];   // [edge][ch], stride 5 (conflict-free)
    __shared__ int   pdL[256];

    if (threadIdx.x < 114) {
        WfL[threadIdx.x] = Wf1[threadIdx.x] * LOG2E;
        WsL[threadIdx.x] = Ws1[threadIdx.x] * LOG2E;
    }
    if (threadIdx.x < 3) {
        bfL[threadIdx.x] = bf1[threadIdx.x] * LOG2E;
        bsL[threadIdx.x] = bs1[threadIdx.x] * LOG2E;
    }
    __syncthreads();

    const int p = blockIdx.x * 256 + threadIdx.x;   // 800000 % 256 == 0
    int4 e = epack[p];
    const int eid = e.x, s = e.y, d = e.z;
    pdL[threadIdx.x] = d;

    float z[38];
    z[0] = x[d*3+0]; z[1] = x[d*3+1]; z[2] = x[d*3+2];
    z[3] = x[s*3+0]; z[4] = x[s*3+1]; z[5] = x[s*3+2];
    const float4* ep = (const float4*)(EA + (size_t)eid * EDGE_DIM);
    #pragma unroll
    for (int q = 0; q < 8; ++q) {
        float4 v = ep[q];
        z[6+4*q+0] = v.x; z[6+4*q+1] = v.y; z[6+4*q+2] = v.z; z[6+4*q+3] = v.w;
    }

    if (EAb) {   // uniform branch: emit sorted bf16 edge attrs
        unsigned short vals[32];
        #pragma unroll
        for (int j = 0; j < 32; ++j) vals[j] = f2bf(z[6+j]);
        unsigned short* dst = EAb + (size_t)p * 32;
        *(short8*)(dst + 0)  = *(short8*)(vals + 0);
        *(short8*)(dst + 8)  = *(short8*)(vals + 8);
        *(short8*)(dst + 16) = *(short8*)(vals + 16);
        *(short8*)(dst + 24) = *(short8*)(vals + 24);
    }

    float f[3], g[3];
    #pragma unroll
    for (int c = 0; c < 3; ++c) { f[c] = bfL[c]; g[c] = bsL[c]; }
    #pragma unroll
    for (int j = 0; j < 38; ++j) {
        #pragma unroll
        for (int c = 0; c < 3; ++c) {
            f[c] += z[j] * WfL[j*3+c];
            g[c] += z[j] * WsL[j*3+c];
        }
    }
    #pragma unroll
    for (int c = 0; c < 3; ++c) {
        float sig = __builtin_amdgcn_rcpf(1.0f + __builtin_amdgcn_exp2f(-f[c]));
        float sp  = __builtin_amdgcn_logf(1.0f + __builtin_amdgcn_exp2f(g[c]));
        msgL[threadIdx.x*5 + c] = sig * sp;
    }
    __syncthreads();

    // Segmented reduction: 48 threads = 3 channels x 16 segments of 16 edges.
    if (threadIdx.x < 48) {
        const int c   = threadIdx.x % 3;
        const int seg = threadIdx.x / 3;
        const int base = seg * 16;
        float acc = 0.0f;
        int cur = pdL[base];
        #pragma unroll 4
        for (int i = 0; i < 16; ++i) {
            int dd = pdL[base + i];
            float v = msgL[(base + i)*5 + c];
            if (dd != cur) {
                atomicAdd(agg0 + (size_t)cur*3 + c, acc);
                acc = 0.0f; cur = dd;
            }
            acc += v;
        }
        atomicAdd(agg0 + (size_t)cur*3 + c, acc);
    }
}

// ---------------------------------------------------------------------------
// hist + weight repack fused. Stores rank[e] (the atomicAdd return) so
// scatter needs no atomics; rank parks in the Pb region (overwritten later).
// ---------------------------------------------------------------------------
__global__ __launch_bounds__(256) void hist_repack_kernel(
    const int* __restrict__ ei, int* __restrict__ hist, int* __restrict__ rank,
    const float* __restrict__ Wf, const float* __restrict__ Ws,
    unsigned short* __restrict__ Bfrag, unsigned short* __restrict__ BE)
{
    int e = blockIdx.x * 256 + threadIdx.x;
    if (e < N_EDGES) rank[e] = atomicAdd(&hist[ei[N_EDGES + e]], 1);

    int idx = e;
    if (idx < 2*32*4*64) {          // node-path: 16384 frags
        int lane = idx & 63;
        int kc   = (idx >> 6) & 3;
        int nt   = (idx >> 8) & 31;
        int l    = idx >> 13;
        const float* wf  = Wf + (size_t)l * ZIN * HIDDEN;
        const float* wsp = Ws + (size_t)l * ZIN * HIDDEN;
        int n = nt*16 + (lane & 15);
        int half = n >> 8;
        int within = n & 255;
        int cc = within >> 1;
        int t = within & 1;
        const float* W = t ? wsp : wf;
        unsigned short vals[8];
        #pragma unroll
        for (int j = 0; j < 8; ++j) {
            int k = kc*32 + (lane >> 4)*8 + j;
            vals[j] = f2bf(W[(size_t)(half*128 + k)*128 + cc] * LOG2E);
        }
        *(short8*)(Bfrag + (size_t)idx * 8) = *(short8*)vals;
    } else if (idx < 2*32*4*64 + 2*16*64) {   // edge-path: 2048 frags
        int i2 = idx - 2*32*4*64;
        int lane = i2 & 63;
        int nt   = (i2 >> 6) & 15;
        int l    = i2 >> 10;
        const float* W = ((nt & 8) ? Ws : Wf) + (size_t)l * ZIN * HIDDEN + 256*128;
        int c = (nt & 7)*16 + (lane & 15);
        unsigned short vals[8];
        #pragma unroll
        for (int j = 0; j < 8; ++j) {
            int k = (lane >> 4)*8 + j;
            vals[j] = f2bf(W[(size_t)k*128 + c] * LOG2E);
        }
        *(short8*)(BE + (size_t)i2 * 8) = *(short8*)vals;
    }
}

__global__ __launch_bounds__(256) void scanA_kernel(
    const int* __restrict__ hist, int* __restrict__ cursor, int* __restrict__ btot)
{
    __shared__ int tmp[256];
    int t = threadIdx.x;
    int i = blockIdx.x * 256 + t;
    int v = hist[i];
    tmp[t] = v;
    __syncthreads();
    #pragma unroll
    for (int off = 1; off < 256; off <<= 1) {
        int y = (t >= off) ? tmp[t - off] : 0;
        __syncthreads();
        if (t >= off) tmp[t] += y;
        __syncthreads();
    }
    cursor[i] = tmp[t] - v;
    if (t == 255) btot[blockIdx.x] = tmp[t];
}

__global__ __launch_bounds__(256) void scanB_kernel(int* __restrict__ btot)
{
    __shared__ int tmp[256];
    int t = threadIdx.x;
    int v = btot[t];
    tmp[t] = v;
    __syncthreads();
    #pragma unroll
    for (int off = 1; off < 256; off <<= 1) {
        int y = (t >= off) ? tmp[t - off] : 0;
        __syncthreads();
        if (t >= off) tmp[t] += y;
        __syncthreads();
    }
    btot[t] = tmp[t] - v;
}

// Scatter: one int4 store per edge (eid, src, dst, 0) at its sorted slot.
// slot = cursor[d] + rank[e] + btot[d>>8] -- no atomics, deterministic.
__global__ __launch_bounds__(256) void scatter_kernel(
    const int* __restrict__ ei, const int* __restrict__ cursor,
    const int* __restrict__ btot, const int* __restrict__ rank,
    int4* __restrict__ epack)
{
    int e = blockIdx.x * 256 + threadIdx.x;
    if (e >= N_EDGES) return;
    int s = ei[e];
    int d = ei[N_EDGES + e];
    int p = cursor[d] + rank[e] + btot[d >> 8];
    epack[p] = make_int4(e, s, d, 0);
}

// ---------------------------------------------------------------------------
// gemm0 with proj fused: A-row = relu(bp + (x+ln2*agg0)@Wp), computed
// in-block from the 3-dim inputs (Wp/bp in LDS); H stored once (colBase==0).
// Then Pb = bf16(A @ (log2e*Wcat) + log2e*bias) as before.
// ---------------------------------------------------------------------------
__global__ __launch_bounds__(256) void gemm0_fused_kernel(
    const float* __restrict__ x, const float* __restrict__ agg0,
    const float* __restrict__ Wp, const float* __restrict__ bp,
    const unsigned short* __restrict__ Bfrag,
    const float* __restrict__ bf, const float* __restrict__ bs,
    unsigned short* __restrict__ Pb, float* __restrict__ H)
{
    __shared__ float WpL[384], bpL[128];
    WpL[threadIdx.x] = Wp[threadIdx.x];
    if (threadIdx.x < 128) {
        WpL[256 + threadIdx.x] = Wp[256 + threadIdx.x];
        bpL[threadIdx.x] = bp[threadIdx.x];
    }
    __syncthreads();

    const int lane = threadIdx.x & 63;
    const int wave = threadIdx.x >> 6;
    const int m    = lane & 15;
    const int quad = lane >> 4;
    const int rowA = blockIdx.y * 64 + wave * 16 + m;
    const int rowX = rowA < N_NODES ? rowA : N_NODES - 1;   // clamp input reads
    const int colBase = blockIdx.x * 256;

    float h0 = fmaf(agg0[rowX*3+0], LN2, x[rowX*3+0]);
    float h1 = fmaf(agg0[rowX*3+1], LN2, x[rowX*3+1]);
    float h2 = fmaf(agg0[rowX*3+2], LN2, x[rowX*3+2]);

    short8 a[4];
    #pragma unroll
    for (int kc = 0; kc < 4; ++kc) {
        float vv[8];
        unsigned short t[8];
        #pragma unroll
        for (int i = 0; i < 8; ++i) {
            int col = kc*32 + quad*8 + i;
            float v = bpL[col] + h0*WpL[col] + h1*WpL[128+col] + h2*WpL[256+col];
            v = fmaxf(v, 0.0f);
            vv[i] = v;
            t[i] = f2bf(v);
        }
        a[kc] = *(short8*)t;
        if (colBase == 0 && rowA < N_NODES) {
            float* hp = H + (size_t)rowA * 128 + kc*32 + quad*8;
            *(float4*)hp       = make_float4(vv[0], vv[1], vv[2], vv[3]);
            *(float4*)(hp + 4) = make_float4(vv[4], vv[5], vv[6], vv[7]);
        }
    }

    f32x4 acc[16];
    #pragma unroll
    for (int nt = 0; nt < 16; ++nt) {
        float bias = 0.0f;
        if (colBase == 0) {
            int col = nt*16 + m;
            bias = ((col & 1) ? bs[col >> 1] : bf[col >> 1]) * LOG2E;
        }
        acc[nt] = (f32x4){bias, bias, bias, bias};
    }

    #pragma unroll
    for (int nt = 0; nt < 16; ++nt) {
        int ntg = (colBase >> 4) + nt;
        const unsigned short* bpf = Bfrag + ((size_t)(ntg*4) * 64 + lane) * 8;
        #pragma unroll
        for (int kc = 0; kc < 4; ++kc) {
            short8 b = *(const short8*)(bpf + (size_t)kc * 64 * 8);
            acc[nt] = __builtin_amdgcn_mfma_f32_16x16x32_bf16(a[kc], b, acc[nt], 0, 0, 0);
        }
    }

    const int rowC = blockIdx.y * 64 + wave * 16 + quad * 4;
    #pragma unroll
    for (int nt = 0; nt < 16; ++nt) {
        int col = colBase + nt*16 + m;
        #pragma unroll
        for (int r = 0; r < 4; ++r) {
            int row = rowC + r;
            if (row < N_NODES) Pb[(size_t)row * 512 + col] = f2bf(acc[nt][r]);
        }
    }
}

// ---------------------------------------------------------------------------
// Node MFMA GEMM (layer 1): A = relu(H + ln2*aggIn), fused into the A-load.
// ---------------------------------------------------------------------------
__global__ __launch_bounds__(256) void gemm_mfma(
    const float* __restrict__ H, const float* __restrict__ aggIn,
    const unsigned short* __restrict__ Bfrag,
    const float* __restrict__ bf, const float* __restrict__ bs,
    unsigned short* __restrict__ Pb)
{
    const int lane = threadIdx.x & 63;
    const int wave = threadIdx.x >> 6;
    const int m    = lane & 15;
    const int quad = lane >> 4;
    const int rowA = blockIdx.y * 64 + wave * 16 + m;   // OOB rows read ws (safe); stores masked
    const int colBase = blockIdx.x * 256;

    const float* hrow = H + (size_t)rowA * 128;
    const float* arow = aggIn + (size_t)rowA * 128;
    short8 a[4];
    #pragma unroll
    for (int kc = 0; kc < 4; ++kc) {
        float4 v0 = *(const float4*)(hrow + kc*32 + quad*8);
        float4 v1 = *(const float4*)(hrow + kc*32 + quad*8 + 4);
        float4 a0 = *(const float4*)(arow + kc*32 + quad*8);
        float4 a1 = *(const float4*)(arow + kc*32 + quad*8 + 4);
        v0.x = fmaxf(fmaf(a0.x, LN2, v0.x), 0.f); v0.y = fmaxf(fmaf(a0.y, LN2, v0.y), 0.f);
        v0.z = fmaxf(fmaf(a0.z, LN2, v0.z), 0.f); v0.w = fmaxf(fmaf(a0.w, LN2, v0.w), 0.f);
        v1.x = fmaxf(fmaf(a1.x, LN2, v1.x), 0.f); v1.y = fmaxf(fmaf(a1.y, LN2, v1.y), 0.f);
        v1.z = fmaxf(fmaf(a1.z, LN2, v1.z), 0.f); v1.w = fmaxf(fmaf(a1.w, LN2, v1.w), 0.f);
        unsigned short t[8];
        t[0]=f2bf(v0.x); t[1]=f2bf(v0.y); t[2]=f2bf(v0.z); t[3]=f2bf(v0.w);
        t[4]=f2bf(v1.x); t[5]=f2bf(v1.y); t[6]=f2bf(v1.z); t[7]=f2bf(v1.w);
        a[kc] = *(short8*)t;
    }

    f32x4 acc[16];
    #pragma unroll
    for (int nt = 0; nt < 16; ++nt) {
        float bias = 0.0f;
        if (colBase == 0) {
            int col = nt*16 + m;
            bias = ((col & 1) ? bs[col >> 1] : bf[col >> 1]) * LOG2E;
        }
        acc[nt] = (f32x4){bias, bias, bias, bias};
    }

    #pragma unroll
    for (int nt = 0; nt < 16; ++nt) {
        int ntg = (colBase >> 4) + nt;
        const unsigned short* bp = Bfrag + ((size_t)(ntg*4) * 64 + lane) * 8;
        #pragma unroll
        for (int kc = 0; kc < 4; ++kc) {
            short8 b = *(const short8*)(bp + (size_t)kc * 64 * 8);
            acc[nt] = __builtin_amdgcn_mfma_f32_16x16x32_bf16(a[kc], b, acc[nt], 0, 0, 0);
        }
    }

    const int rowC = blockIdx.y * 64 + wave * 16 + quad * 4;
    #pragma unroll
    for (int nt = 0; nt < 16; ++nt) {
        int col = colBase + nt*16 + m;
        #pragma unroll
        for (int r = 0; r < 4; ++r) {
            int row = rowC + r;
            if (row < N_NODES) Pb[(size_t)row * 512 + col] = f2bf(acc[nt][r]);
        }
    }
}

// ---------------------------------------------------------------------------
// Fused edge kernel, v18: depth-2 named-scalar gather batching + sched_barrier
// pin, now with __launch_bounds__(256, 6) -> VGPR cap ~85 so the 16-load
// batch can be REGISTER-resident (R8/R10 spilled under the 64-cap; R9 was
// rescheduled away). Occupancy 8->6 blocks/CU traded for 2x fewer gather
// latency waits. Reduce unchanged (4x16 segments, interior-run plain stores).
// ---------------------------------------------------------------------------
__global__ __launch_bounds__(256, 6) void edge_kernel(
    const unsigned short* __restrict__ Pb, const float* __restrict__ EA,
    const unsigned short* __restrict__ EAb,
    const int4* __restrict__ epack,
    const unsigned short* __restrict__ BE,
    float* __restrict__ agg)
{
    __shared__ float msgL[64*68];           // 17.4 KB, [c-row][swizzled 4-edge chunks]
    __shared__ int pdL[64];
    __shared__ unsigned bmaskL[2];

    if (threadIdx.x < 64) {
        const int t = threadIdx.x;
        int d = epack[blockIdx.x*64 + t].z;
        pdL[t] = d;
        bool b = (t & 15) ? (d != pdL[t-1]) : false;   // zero bits 0,16,32,48 (seg starts)
        unsigned long long bal = __ballot(b);
        if (t == 0) { bmaskL[0] = (unsigned)bal; bmaskL[1] = (unsigned)(bal >> 32); }
    }

    const int lane = threadIdx.x & 63;
    const int wave = threadIdx.x >> 6;
    const int m    = lane & 15;
    const int quad = lane >> 4;
    const int p0   = blockIdx.x * 64 + wave * 16;   // 800000 % 64 == 0

    // A-frag: this lane's edge attrs (bf16)
    short8 a;
    if (EAb) {   // direct coalesced load, address known at entry
        a = *(const short8*)(EAb + (size_t)(p0 + m) * 32 + quad*8);
    } else {
        int eid = epack[p0 + m].x;
        const float* ea = EA + (size_t)eid * EDGE_DIM + quad*8;
        float4 v0 = *(const float4*)ea;
        float4 v1 = *(const float4*)(ea + 4);
        unsigned short t[8];
        t[0]=f2bf(v0.x); t[1]=f2bf(v0.y); t[2]=f2bf(v0.z); t[3]=f2bf(v0.w);
        t[4]=f2bf(v1.x); t[5]=f2bf(v1.y); t[6]=f2bf(v1.z); t[7]=f2bf(v1.w);
        a = *(short8*)t;
    }

    // Per-r base pointers: nt offsets become compile-time immediates.
    const unsigned short* pdp[4];
    const unsigned short* psp[4];
    #pragma unroll
    for (int r = 0; r < 4; ++r) {
        int4 e = epack[p0 + quad*4 + r];
        pdp[r] = Pb + (size_t)e.z * 512 + 2*m;
        psp[r] = Pb + (size_t)e.y * 512 + 256 + 2*m;
    }

    const short8* BEv = (const short8*)BE;   // 16 KB, L1-resident
    const int chunk  = wave*4 + quad;        // this thread's 4-edge chunk (0..15)
    const int c2  = threadIdx.x & 63;        // reduce: channel row
    const int seg = threadIdx.x >> 6;        // reduce: 16-edge segment (== wave)
    const int chunkp = (chunk + 2*m) & 15;   // rotate-swizzle

    #pragma unroll
    for (int half = 0; half < 2; ++half) {
        #pragma unroll
        for (int pair = 0; pair < 2; ++pair) {
            const int ntA = half*4 + pair*2;
            const int ntB = ntA + 1;
            // ---- batch-issue 16 gather loads (named scalars) ----
            unsigned pdA0 = *(const unsigned*)(pdp[0] + ntA*32);
            unsigned psA0 = *(const unsigned*)(psp[0] + ntA*32);
            unsigned pdA1 = *(const unsigned*)(pdp[1] + ntA*32);
            unsigned psA1 = *(const unsigned*)(psp[1] + ntA*32);
            unsigned pdA2 = *(const unsigned*)(pdp[2] + ntA*32);
            unsigned psA2 = *(const unsigned*)(psp[2] + ntA*32);
            unsigned pdA3 = *(const unsigned*)(pdp[3] + ntA*32);
            unsigned psA3 = *(const unsigned*)(psp[3] + ntA*32);
            unsigned pdB0 = *(const unsigned*)(pdp[0] + ntB*32);
            unsigned psB0 = *(const unsigned*)(psp[0] + ntB*32);
            unsigned pdB1 = *(const unsigned*)(pdp[1] + ntB*32);
            unsigned psB1 = *(const unsigned*)(psp[1] + ntB*32);
            unsigned pdB2 = *(const unsigned*)(pdp[2] + ntB*32);
            unsigned psB2 = *(const unsigned*)(psp[2] + ntB*32);
            unsigned pdB3 = *(const unsigned*)(pdp[3] + ntB*32);
            unsigned psB3 = *(const unsigned*)(psp[3] + ntB*32);
            // Fence: loads above may NOT sink below; compute below may not hoist.
            __builtin_amdgcn_sched_barrier(0);

            f32x4 accFA, accSA, accFB, accSB;
            accFA[0] = bf_lo(pdA0) + bf_lo(psA0); accSA[0] = bf_hi(pdA0) + bf_hi(psA0);
            accFA[1] = bf_lo(pdA1) + bf_lo(psA1); accSA[1] = bf_hi(pdA1) + bf_hi(psA1);
            accFA[2] = bf_lo(pdA2) + bf_lo(psA2); accSA[2] = bf_hi(pdA2) + bf_hi(psA2);
            accFA[3] = bf_lo(pdA3) + bf_lo(psA3); accSA[3] = bf_hi(pdA3) + bf_hi(psA3);
            accFB[0] = bf_lo(pdB0) + bf_lo(psB0); accSB[0] = bf_hi(pdB0) + bf_hi(psB0);
            accFB[1] = bf_lo(pdB1) + bf_lo(psB1); accSB[1] = bf_hi(pdB1) + bf_hi(psB1);
            accFB[2] = bf_lo(pdB2) + bf_lo(psB2); accSB[2] = bf_hi(pdB2) + bf_hi(psB2);
            accFB[3] = bf_lo(pdB3) + bf_lo(psB3); accSB[3] = bf_hi(pdB3) + bf_hi(psB3);

            // ---- MFMA + activation + LDS write for both nt of the pair ----
            short8 bFA = BEv[ntA*64 + lane];
            short8 bSA = BEv[(ntA+8)*64 + lane];
            short8 bFB = BEv[ntB*64 + lane];
            short8 bSB = BEv[(ntB+8)*64 + lane];
            f32x4 qfA = __builtin_amdgcn_mfma_f32_16x16x32_bf16(a, bFA, accFA, 0, 0, 0);
            f32x4 qsA = __builtin_amdgcn_mfma_f32_16x16x32_bf16(a, bSA, accSA, 0, 0, 0);
            f32x4 qfB = __builtin_amdgcn_mfma_f32_16x16x32_bf16(a, bFB, accFB, 0, 0, 0);
            f32x4 qsB = __builtin_amdgcn_mfma_f32_16x16x32_bf16(a, bSB, accSB, 0, 0, 0);

            float4 mvA, mvB;
            #pragma unroll
            for (int r = 0; r < 4; ++r) {
                float sigA = __builtin_amdgcn_rcpf(1.0f + __builtin_amdgcn_exp2f(-qfA[r]));
                float spA  = __builtin_amdgcn_logf(1.0f + __builtin_amdgcn_exp2f(qsA[r]));
                ((float*)&mvA)[r] = sigA * spA;
                float sigB = __builtin_amdgcn_rcpf(1.0f + __builtin_amdgcn_exp2f(-qfB[r]));
                float spB  = __builtin_amdgcn_logf(1.0f + __builtin_amdgcn_exp2f(qsB[r]));
                ((float*)&mvB)[r] = sigB * spB;
            }
            const int rowA_ = (pair*2)*16 + m;       // channel row within this half
            const int rowB_ = (pair*2+1)*16 + m;
            *(float4*)&msgL[rowA_*68 + chunkp*4] = mvA;  // ds_write_b128
            *(float4*)&msgL[rowB_*68 + chunkp*4] = mvB;  // ds_write_b128
        }
        __syncthreads();

        // Segmented reduction: 256 threads = 64 channels x 4 segments of 16.
        // Interior runs -> plain store (unique writer); boundary runs -> atomic.
        {
            unsigned mfull = bmaskL[seg >> 1];
            unsigned msk = (unsigned)__builtin_amdgcn_readfirstlane(
                (int)((mfull >> ((seg & 1) * 16)) & 0xFFFEu));
            const int swz = 2*(c2 & 15);
            const float* rowp = &msgL[c2*68];
            float* aggc = agg + half*64 + c2;
            const int base = seg*16;
            float acc = 0.0f;
            bool inside = false;
            #pragma unroll
            for (int jj = 0; jj < 4; ++jj) {
                const int ch = seg*4 + jj;
                const float4 v4 = *(const float4*)&rowp[((ch + swz) & 15)*4];  // ds_read_b128
                #pragma unroll
                for (int k = 0; k < 4; ++k) {
                    if (msk & 1u) {
                        float* dp = &aggc[(size_t)pdL[base + jj*4 + k - 1] * HIDDEN];
                        if (inside) *dp = acc; else atomicAdd(dp, acc);
                        acc = 0.0f; inside = true;
                    }
                    msk >>= 1;
                    acc += ((const float*)&v4)[k];
                }
            }
            atomicAdd(&aggc[(size_t)pdL[base + 15] * HIDDEN], acc);
        }
        if (half == 0) __syncthreads();   // protect msgL reuse by phase 2
    }
}

// ---------------------------------------------------------------------------
// Pool with fused double update: h = relu(relu(H+ln2*agg1)+ln2*agg2).
// ---------------------------------------------------------------------------
__global__ __launch_bounds__(128) void pool_kernel(
    const float* __restrict__ H, const float* __restrict__ agg1,
    const float* __restrict__ agg2, const int* __restrict__ batch,
    float* __restrict__ gsum, float* __restrict__ gcnt)
{
    const int c = threadIdx.x;
    const int n0 = blockIdx.x * 32;
    float acc = 0.0f;
    int cur = -1;
    for (int i = 0; i < 32; ++i) {
        int n = n0 + i;
        if (n >= N_NODES) break;
        int g = batch[n];
        if (g != cur) {
            if (cur >= 0) atomicAdd(gsum + (size_t)cur * HIDDEN + c, acc);
            cur = g; acc = 0.0f;
        }
        size_t ix = (size_t)n * HIDDEN + c;
        float h = fmaxf(fmaf(agg2[ix], LN2, fmaxf(fmaf(agg1[ix], LN2, H[ix]), 0.0f)), 0.0f);
        acc += h;
    }
    if (cur >= 0) atomicAdd(gsum + (size_t)cur * HIDDEN + c, acc);

    if (c == 0) {
        int curg = -1; float run = 0.0f;
        for (int i = 0; i < 32; ++i) {
            int n = n0 + i;
            if (n >= N_NODES) break;
            int g = batch[n];
            if (g != curg) {
                if (curg >= 0) atomicAdd(gcnt + curg, run);
                curg = g; run = 0.0f;
            }
            run += 1.0f;
        }
        if (curg >= 0) atomicAdd(gcnt + curg, run);
    }
}

// ---------------------------------------------------------------------------
// Final MLP: g = relu((gsum/cnt) @ W1 + b1); out = g @ Wh^T + bh
// ---------------------------------------------------------------------------
__global__ __launch_bounds__(128) void head_kernel(
    const float* __restrict__ gsum, const float* __restrict__ gcnt,
    const float* __restrict__ W1, const float* __restrict__ b1,
    const float* __restrict__ Wh, const float* __restrict__ bh,
    float* __restrict__ out)
{
    __shared__ float gavg[128];
    __shared__ float g1[128];
    const int g = blockIdx.x, c = threadIdx.x;
    float cnt = fmaxf(gcnt[g], 1.0f);
    gavg[c] = gsum[(size_t)g * HIDDEN + c] / cnt;
    __syncthreads();
    float acc = b1[c];
    for (int k = 0; k < 128; ++k) acc += gavg[k] * W1[k*128 + c];
    g1[c] = fmaxf(acc, 0.0f);
    __syncthreads();
    if (c < 5) {
        float o = bh[c];
        for (int k = 0; k < 128; ++k) o += g1[k] * Wh[c*128 + k];
        out[(size_t)g * 5 + c] = o;
    }
}

// ---------------------------------------------------------------------------
// Launch
// ---------------------------------------------------------------------------
extern "C" void kernel_launch(void* const* d_in, const int* in_sizes, int n_in,
                              void* d_out, int out_size, void* d_ws, size_t ws_size,
                              hipStream_t stream) {
    const float* x        = (const float*)d_in[0];
    const int*   ei       = (const int*)  d_in[1];
    const float* EA       = (const float*)d_in[2];
    const int*   batch    = (const int*)  d_in[3];
    const float* Wf1      = (const float*)d_in[4];
    const float* bf1      = (const float*)d_in[5];
    const float* Ws1      = (const float*)d_in[6];
    const float* bs1      = (const float*)d_in[7];
    const float* Wp       = (const float*)d_in[8];
    const float* bp       = (const float*)d_in[9];
    const float* Wf_convs = (const float*)d_in[10];
    const float* bf_convs = (const float*)d_in[11];
    const float* Ws_convs = (const float*)d_in[12];
    const float* bs_convs = (const float*)d_in[13];
    const float* W1       = (const float*)d_in[14];
    const float* b1       = (const float*)d_in[15];
    const float* W_heads  = (const float*)d_in[16];
    const float* b_heads  = (const float*)d_in[17];
    float* out = (float*)d_out;

    float* ws = (float*)d_ws;
    // workspace layout (float units); agg1/agg2/agg0 contiguous for one memset
    float* H    = ws + 0;                                     // 6,400,000
    unsigned short* Pb = (unsigned short*)(ws + 6400000);     // 25.6M ushort
    float* agg1 = ws + 19200000;                              // 6,400,000
    float* agg2 = ws + 25600000;                              // 6,400,000
    float* agg0 = ws + 32000000;                              // 150,016
    unsigned short* Bfrag = (unsigned short*)(ws + 32150016); // 131072 ushort
    unsigned short* BE    = (unsigned short*)(ws + 32215552); // 16384 ushort
    float* gsum = ws + 32223744;                              // 32768
    float* gcnt = ws + 32256512;                              // 512
    int* hist   = (int*)(ws + 32257024);                      // NPAD
    int* cursor = (int*)(ws + 32307200);                      // NPAD
    int* btot   = (int*)(ws + 32357376);                      // 256
    int4* epack = (int4*)(ws + 32357632);                     // 800000 int4 = 3.2M floats
    unsigned short* EAb = (unsigned short*)(ws + 35557632);   // 25.6M ushort (optional)
    const size_t need_eab = (size_t)(35557632 + 12800000) * 4;
    unsigned short* EAb_use = (ws_size >= need_eab) ? EAb : (unsigned short*)nullptr;
    // rank parks in the Pb region: produced by hist, consumed by scatter,
    // then Pb is fully overwritten by gemm0 (first Pb producer).
    int* rank = (int*)Pb;

    // ---- upfront memsets ----
    hipMemsetAsync(hist, 0, (size_t)NPAD * sizeof(int), stream);
    hipMemsetAsync(agg1, 0, (size_t)(2 * N_NODES * HIDDEN + 150016) * sizeof(float), stream);
    hipMemsetAsync(gsum, 0, (size_t)(NUM_GRAPHS * HIDDEN + NUM_GRAPHS) * sizeof(float), stream);

    // ---- edge sort by dst (hist fused with weight repack; rank recorded) ----
    hist_repack_kernel<<<(N_EDGES + 255)/256, 256, 0, stream>>>(
        ei, hist, rank, Wf_convs, Ws_convs, Bfrag, BE);
    scanA_kernel<<<NPAD/256, 256, 0, stream>>>(hist, cursor, btot);
    scanB_kernel<<<1, 256, 0, stream>>>(btot);
    scatter_kernel<<<(N_EDGES + 255)/256, 256, 0, stream>>>(ei, cursor, btot, rank, epack);

    // conv1 (dst-sorted, log2-domain, emits sorted bf16 EA)
    conv1_sorted_kernel<<<N_EDGES/256, 256, 0, stream>>>(
        x, EA, epack, Wf1, bf1, Ws1, bs1, agg0, EAb_use);

    dim3 ggrid(2, (N_NODES + 63)/64);
    // ---- layer 0: proj fused into gemm; A = relu(bp + (x+ln2*agg0)@Wp) ----
    gemm0_fused_kernel<<<ggrid, 256, 0, stream>>>(
        x, agg0, Wp, bp, Bfrag, bf_convs, bs_convs, Pb, H);
    edge_kernel<<<N_EDGES/64, 256, 0, stream>>>(Pb, EA, EAb_use, epack, BE, agg1);
    // ---- layer 1: A = relu(H + ln2*agg1), fused ----
    gemm_mfma<<<ggrid, 256, 0, stream>>>(H, agg1, Bfrag + (size_t)32*4*64*8,
                                         bf_convs + HIDDEN, bs_convs + HIDDEN, Pb);
    edge_kernel<<<N_EDGES/64, 256, 0, stream>>>(Pb, EA, EAb_use, epack,
                                                BE + (size_t)16*64*8, agg2);

    // pool (fused relu(relu(H+ln2*agg1)+ln2*agg2)) + heads
    pool_kernel<<<(N_NODES + 31)/32, 128, 0, stream>>>(H, agg1, agg2, batch, gsum, gcnt);
    head_kernel<<<NUM_GRAPHS, 128, 0, stream>>>(gsum, gcnt, W1, b1, W_heads, b_heads, out);
}